// Round 9
// baseline (3410.686 us; speedup 1.0000x reference)
//
#include <hip/hip_runtime.h>
#include <hip/hip_cooperative_groups.h>
#include <cmath>

namespace cg = cooperative_groups;

#define T_STEPS 512
#define NBLK 256
#define CNT_STRIDE 16  // 64B-padded counter slots

typedef _Float16 h8 __attribute__((ext_vector_type(8)));
typedef float f4 __attribute__((ext_vector_type(4)));
typedef int i32x4 __attribute__((ext_vector_type(4)));
typedef unsigned long long ull_t;

__device__ __forceinline__ float sigm(float v) { return 1.f / (1.f + __expf(-v)); }
__device__ __forceinline__ float tanh_fast(float v) { return 1.f - 2.f / (__expf(2.f * v) + 1.f); }

// ---------------- pack P = emb @ [Wx interleaved] + bias : [513][4096] fp32 (exact input path)
__global__ void pack_P(const float* __restrict__ emb,
                       const float* __restrict__ Wgx, const float* __restrict__ Wix,
                       const float* __restrict__ Wfx, const float* __restrict__ Wox,
                       const float* __restrict__ bg, const float* __restrict__ bi,
                       const float* __restrict__ bf_, const float* __restrict__ bo,
                       float* __restrict__ P) {
  __shared__ float es[8][512];
  const int vg = blockIdx.x;   // 0..64
  const int st = blockIdx.y;   // 0..15
  const int tid = threadIdx.x;
  for (int i = tid; i < 8 * 512; i += 256) {
    int vv = i >> 9, k = i & 511;
    int v = vg * 8 + vv;
    es[vv][k] = (v < 513) ? emb[v * 512 + k] : 0.f;
  }
  __syncthreads();
  const int c = st * 256 + tid;
  const int gate = c & 3, unit = c >> 2;
  const float* W = gate == 0 ? Wgx : gate == 1 ? Wix : gate == 2 ? Wfx : Wox;
  const float* bias = gate == 0 ? bg : gate == 1 ? bi : gate == 2 ? bf_ : bo;
  float acc[8];
  const float bv = bias[unit];
#pragma unroll
  for (int vv = 0; vv < 8; vv++) acc[vv] = bv;
  for (int k = 0; k < 512; k++) {
    float w = W[k * 1024 + unit];
#pragma unroll
    for (int vv = 0; vv < 8; vv++) acc[vv] += es[vv][k] * w;
  }
#pragma unroll
  for (int vv = 0; vv < 8; vv++) {
    int v = vg * 8 + vv;
    if (v < 513) P[(size_t)v * 4096 + c] = acc[vv];
  }
}

// ---------------- pack Wt[c][k] = W_{gate(c)}h[k][unit(c)] as fp16
__global__ void pack_Wt(const float* __restrict__ Wgh, const float* __restrict__ Wih,
                        const float* __restrict__ Wfh, const float* __restrict__ Woh,
                        _Float16* __restrict__ Wt) {
  const int c = blockIdx.x;
  const int gate = c & 3, unit = c >> 2;
  const float* W = gate == 0 ? Wgh : gate == 1 ? Wih : gate == 2 ? Wfh : Woh;
  for (int k = threadIdx.x; k < 1024; k += 256)
    Wt[(size_t)c * 1024 + k] = (_Float16)W[k * 1024 + unit];
}

// ---------------- persistent LSTM: 16 independent groups of 8 batch rows,
// TWO groups software-pipelined per block. Block b: family gA=b&7 serves
// groups gA (rows 8gA..+8) and gB=gA+8 (rows 64+8gA..+8) with the SAME
// 128 gate-cols (sub=b>>3) and the SAME B-registers.
// half(X,t): wave0 {add cnt[other], spin} || waves1-4 stage h_X(t) ||
// gate-threads P-gather -> bar -> MFMA (16-row tile, 8 valid) -> bar ->
// gates + direct 2B sc1 publish of h_X(t+1) -> bar (drains stores).
// Counter protocol: each block's add in half(X,t) certifies ITS publish of the
// OTHER group's h (drained at the previous half's ending barrier). Spin target
// 32(t+1) (t=0 adds are a benign pre-credit of the grid.sync'd h(0)).
// Double-buffer safety: a block adds cnt for group X only after its stage-read
// of X's older buffer completed (program order through barriers).
__launch_bounds__(512, 2)
__global__ void lstm_step_all(const int* __restrict__ x,
                              const float* __restrict__ P,
                              const _Float16* __restrict__ Wt,
                              _Float16* __restrict__ hbuf,
                              float* __restrict__ h32,
                              const float* __restrict__ h_init,
                              const float* __restrict__ c_init,
                              unsigned int* __restrict__ cnt) {
  cg::grid_group grid = cg::this_grid();
  __shared__ _Float16 alds[16 * 1024];  // 32 KB; rows 8-15 never written (garbage ok)
  __shared__ float pre[8 * 132];        // 4.2 KB fp32 pre-activations (valid rows only)
  __shared__ int xs2[2][16];            // [parity][0..7 = A rows, 8..15 = B rows]
  const int tid = threadIdx.x;
  const int blk = blockIdx.x;
  const int gA = blk & 7;
  const int gB = gA + 8;
  const int sub = blk >> 3;       // 0..31 col-partition
  const int lane = tid & 63;
  const int wid = tid >> 6;
  const int l15 = lane & 15;
  const int gg = lane >> 4;
  const int kg = gg * 8;
  const int colbase = sub * 128;
  const int ubase = sub * 32;
  const int rowA = gA * 8;
  const int rowB = 64 + gA * 8;

  if (blk < 16 && tid == 0)
    __hip_atomic_store(&cnt[blk * CNT_STRIDE], 0u, __ATOMIC_RELAXED, __HIP_MEMORY_SCOPE_AGENT);

  // B fragments resident in VGPRs (shared by both groups)
  h8 bfr[32];
  {
    const _Float16* wp = Wt + (size_t)(colbase + wid * 16 + l15) * 1024 + kg;
#pragma unroll
    for (int s = 0; s < 32; s++) bfr[s] = *(const h8*)(wp + s * 32);
  }

  // init h0 for both groups' slices (buffer 0)
  if (tid < 128) {
    int r16 = tid >> 3, q = tid & 7;
    int row = r16 < 8 ? rowA + r16 : rowB + (r16 - 8);
    union { _Float16 h[4]; ull_t u; } pk;
#pragma unroll
    for (int u = 0; u < 4; u++) pk.h[u] = (_Float16)h_init[ubase + q * 4 + u];
    *(ull_t*)&hbuf[(size_t)row * 1024 + ubase + q * 4] = pk.u;
  }
  if (tid < 16) {
    int row = tid < 8 ? rowA + tid : rowB + (tid - 8);
    xs2[0][tid] = x[row * 513];
  }
  // gate threads: tid 256..511 own (row = (tid-256)>>5, unit = tid&31)
  const int grow = (tid - 256) >> 5;
  const int gu = tid & 31;
  float cstA = 0.f, cstB = 0.f;
  if (tid >= 256) { cstA = c_init[ubase + gu]; cstB = cstA; }
  grid.sync();  // covers h0, counters, Wt/P reads

// One pipelined half-step for group with row base RB, c-state CST, counter id CIDX,
// xs2 offset XO. DO_XP: prefetch next x (half A only).
#define DO_HALF(RB, CST, CIDX, XO, DO_XP)                                            \
  {                                                                                  \
    if (tid == 0) {                                                                  \
      __hip_atomic_fetch_add(&cnt[(CIDX) * CNT_STRIDE], 1u, __ATOMIC_RELAXED,        \
                             __HIP_MEMORY_SCOPE_AGENT);                              \
      while (__hip_atomic_load(&cnt[(CIDX) * CNT_STRIDE], __ATOMIC_RELAXED,          \
                               __HIP_MEMORY_SCOPE_AGENT) < tgt)                      \
        __builtin_amdgcn_s_sleep(1);                                                 \
    }                                                                                \
    f4 pv = {0.f, 0.f, 0.f, 0.f};                                                    \
    if (tid >= 256)                                                                  \
      pv = *(const f4*)(P + (size_t)xs2[t & 1][(XO) + grow] * 4096 + colbase + gu * 4); \
    if (tid >= 64 && tid < 320) {                                                    \
      int i0 = tid - 64;                                                             \
      i32x4 av[4];                                                                   \
      _Pragma("unroll") for (int r = 0; r < 4; ++r) {                                \
        int fi = r * 256 + i0, ar = fi >> 7, g = fi & 127;                           \
        const _Float16* p = &hc[(size_t)((RB) + ar) * 1024 + g * 8];                 \
        asm volatile("global_load_dwordx4 %0, %1, off sc0 sc1"                       \
                     : "=v"(av[r]) : "v"(p) : "memory");                             \
      }                                                                              \
      asm volatile("s_waitcnt vmcnt(0)" ::: "memory");                               \
      __builtin_amdgcn_sched_barrier(0);                                             \
      _Pragma("unroll") for (int r = 0; r < 4; ++r) {                                \
        int fi = r * 256 + i0, ar = fi >> 7, g = fi & 127;                           \
        *(i32x4*)&alds[ar * 1024 + ((g ^ (ar & 7)) * 8)] = av[r];                    \
      }                                                                              \
    }                                                                                \
    __syncthreads();                                                                 \
    {                                                                                \
      f4 ac0 = {0.f, 0.f, 0.f, 0.f}, ac1 = ac0, ac2 = ac0, ac3 = ac0;                \
      _Pragma("unroll") for (int s = 0; s < 32; ++s) {                               \
        int g = s * 4 + gg;                                                          \
        h8 a = *(const h8*)&alds[l15 * 1024 + ((g ^ (l15 & 7)) * 8)];                \
        if ((s & 3) == 0)                                                            \
          ac0 = __builtin_amdgcn_mfma_f32_16x16x32_f16(a, bfr[s], ac0, 0, 0, 0);     \
        else if ((s & 3) == 1)                                                       \
          ac1 = __builtin_amdgcn_mfma_f32_16x16x32_f16(a, bfr[s], ac1, 0, 0, 0);     \
        else if ((s & 3) == 2)                                                       \
          ac2 = __builtin_amdgcn_mfma_f32_16x16x32_f16(a, bfr[s], ac2, 0, 0, 0);     \
        else                                                                         \
          ac3 = __builtin_amdgcn_mfma_f32_16x16x32_f16(a, bfr[s], ac3, 0, 0, 0);     \
      }                                                                              \
      f4 acc = (ac0 + ac1) + (ac2 + ac3);                                            \
      if (gg < 2) {                                                                  \
        _Pragma("unroll") for (int i2 = 0; i2 < 4; ++i2)                             \
            pre[(gg * 4 + i2) * 132 + wid * 16 + l15] = acc[i2];                     \
      }                                                                              \
    }                                                                                \
    __syncthreads();                                                                 \
    if (tid >= 256) {                                                                \
      f4 q = *(const f4*)&pre[grow * 132 + gu * 4];                                  \
      q += pv;                                                                       \
      float g_ = tanh_fast(q[0]);                                                    \
      float i_ = sigm(q[1]);                                                         \
      float f_ = sigm(q[2]);                                                         \
      float o_ = sigm(q[3]);                                                         \
      (CST) = g_ * i_ + (CST) * f_;                                                  \
      float hv = tanh_fast(CST) * o_;                                                \
      if (t < T_STEPS - 1) {                                                         \
        union { _Float16 hh; unsigned short us; } cv;                                \
        cv.hh = (_Float16)hv;                                                        \
        __hip_atomic_store(                                                          \
            (unsigned short*)&hn[(size_t)((RB) + grow) * 1024 + ubase + gu],         \
            cv.us, __ATOMIC_RELAXED, __HIP_MEMORY_SCOPE_AGENT);                      \
      } else {                                                                       \
        h32[(size_t)((RB) + grow) * 1024 + ubase + gu] = hv;                         \
      }                                                                              \
    }                                                                                \
    if ((DO_XP) && t + 1 < T_STEPS && tid >= 320 && tid < 336) {                     \
      int r = tid - 320;                                                             \
      int row = r < 8 ? rowA + r : rowB + (r - 8);                                   \
      xs2[(t + 1) & 1][r] = x[row * 513 + (t + 1)];                                  \
    }                                                                                \
    __syncthreads(); /* drains publish stores -> next half's add certifies them */   \
  }

  for (int t = 0; t < T_STEPS; t++) {
    const _Float16* hc = hbuf + (t & 1) * (128 * 1024);
    _Float16* hn = hbuf + ((t + 1) & 1) * (128 * 1024);
    const unsigned tgt = 32u * (unsigned)(t + 1);
    DO_HALF(rowA, cstA, gB, 0, 1)
    DO_HALF(rowB, cstB, gA, 8, 0)
  }
#undef DO_HALF
}

// ---------------- final projection p = h_T @ W_ph + b_p (fp32)
__global__ void proj(const float* __restrict__ h32, const float* __restrict__ Wph,
                     const float* __restrict__ bp, float* __restrict__ logits) {
  const int b = blockIdx.x >> 1;
  const int cc = (blockIdx.x & 1) * 256 + threadIdx.x;
  const float* hrow = h32 + b * 1024;
  float acc = bp[cc];
#pragma unroll 4
  for (int k = 0; k < 1024; k++) acc += hrow[k] * Wph[k * 512 + cc];
  logits[b * 512 + cc] = acc;
}

// ---------------- row-wise log_softmax
__global__ void lsm(const float* __restrict__ logits, float* __restrict__ out) {
  const int b = blockIdx.x;
  const int tid = threadIdx.x;
  __shared__ float sm[4];
  __shared__ float se[4];
  float v0 = logits[b * 512 + tid];
  float v1 = logits[b * 512 + 256 + tid];
  float m = fmaxf(v0, v1);
  for (int o = 1; o < 64; o <<= 1) m = fmaxf(m, __shfl_xor(m, o, 64));
  if ((tid & 63) == 0) sm[tid >> 6] = m;
  __syncthreads();
  m = fmaxf(fmaxf(sm[0], sm[1]), fmaxf(sm[2], sm[3]));
  float e = expf(v0 - m) + expf(v1 - m);
  for (int o = 1; o < 64; o <<= 1) e += __shfl_xor(e, o, 64);
  if ((tid & 63) == 0) se[tid >> 6] = e;
  __syncthreads();
  float ls = logf(se[0] + se[1] + se[2] + se[3]) + m;
  out[b * 512 + tid] = v0 - ls;
  out[b * 512 + 256 + tid] = v1 - ls;
}

extern "C" void kernel_launch(void* const* d_in, const int* in_sizes, int n_in,
                              void* d_out, int out_size, void* d_ws, size_t ws_size,
                              hipStream_t stream) {
  const int* x = (const int*)d_in[0];
  const float* emb = (const float*)d_in[1];
  const float* Wgx = (const float*)d_in[2];
  const float* Wgh = (const float*)d_in[3];
  const float* bg = (const float*)d_in[4];
  const float* Wix = (const float*)d_in[5];
  const float* Wih = (const float*)d_in[6];
  const float* bi = (const float*)d_in[7];
  const float* Wfx = (const float*)d_in[8];
  const float* Wfh = (const float*)d_in[9];
  const float* bf = (const float*)d_in[10];
  const float* Wox = (const float*)d_in[11];
  const float* Woh = (const float*)d_in[12];
  const float* bo = (const float*)d_in[13];
  const float* Wph = (const float*)d_in[14];
  const float* bp = (const float*)d_in[15];
  const float* h_init = (const float*)d_in[16];
  const float* c_init = (const float*)d_in[17];

  char* ws = (char*)d_ws;
  float* P = (float*)ws;                                   // 520*4096*4   = 8,519,680
  unsigned int* cnt = (unsigned int*)(ws + (size_t)513 * 4096 * 4);  // P pad rows
  _Float16* Wt = (_Float16*)(ws + 8519680);                // 4096*1024*2  = 8,388,608
  _Float16* hbuf = (_Float16*)(ws + 8519680 + 8388608);    // 2*128*1024*2 = 524,288
  float* h32 = (float*)(ws + 8519680 + 8388608 + 524288);  // 128*1024*4   = 524,288
  float* logits = (float*)(ws + 8519680 + 8388608 + 524288 + 524288);  // 128*512*4

  pack_P<<<dim3(65, 16), 256, 0, stream>>>(emb, Wgx, Wix, Wfx, Wox, bg, bi, bf, bo, P);
  pack_Wt<<<4096, 256, 0, stream>>>(Wgh, Wih, Wfh, Woh, Wt);

  void* args[] = {(void*)&x, (void*)&P, (void*)&Wt, (void*)&hbuf,
                  (void*)&h32, (void*)&h_init, (void*)&c_init, (void*)&cnt};
  hipLaunchCooperativeKernel((void*)lstm_step_all, dim3(NBLK), dim3(512), args, 0, stream);

  proj<<<256, 256, 0, stream>>>(h32, Wph, bp, logits);
  lsm<<<128, 256, 0, stream>>>(logits, (float*)d_out);
}

// Round 11
// 1735.920 us; speedup vs baseline: 1.9648x; 1.9648x over previous
//
#include <hip/hip_runtime.h>
#include <hip/hip_cooperative_groups.h>
#include <cmath>

namespace cg = cooperative_groups;

#define T_STEPS 512
#define NBLK 256
#define FLAG_STRIDE 16  // 64B-padded flag slots

typedef _Float16 h8 __attribute__((ext_vector_type(8)));
typedef float f4 __attribute__((ext_vector_type(4)));
typedef int i32x4 __attribute__((ext_vector_type(4)));
typedef unsigned long long ull_t;

__device__ __forceinline__ float sigm(float v) { return 1.f / (1.f + __expf(-v)); }
__device__ __forceinline__ float tanh_fast(float v) { return 1.f - 2.f / (__expf(2.f * v) + 1.f); }

// ---------------- pack P = emb @ [Wx interleaved] + bias : [513][4096] fp32 (exact input path)
__global__ void pack_P(const float* __restrict__ emb,
                       const float* __restrict__ Wgx, const float* __restrict__ Wix,
                       const float* __restrict__ Wfx, const float* __restrict__ Wox,
                       const float* __restrict__ bg, const float* __restrict__ bi,
                       const float* __restrict__ bf_, const float* __restrict__ bo,
                       float* __restrict__ P) {
  __shared__ float es[8][512];
  const int vg = blockIdx.x;   // 0..64
  const int st = blockIdx.y;   // 0..15
  const int tid = threadIdx.x;
  for (int i = tid; i < 8 * 512; i += 256) {
    int vv = i >> 9, k = i & 511;
    int v = vg * 8 + vv;
    es[vv][k] = (v < 513) ? emb[v * 512 + k] : 0.f;
  }
  __syncthreads();
  const int c = st * 256 + tid;
  const int gate = c & 3, unit = c >> 2;
  const float* W = gate == 0 ? Wgx : gate == 1 ? Wix : gate == 2 ? Wfx : Wox;
  const float* bias = gate == 0 ? bg : gate == 1 ? bi : gate == 2 ? bf_ : bo;
  float acc[8];
  const float bv = bias[unit];
#pragma unroll
  for (int vv = 0; vv < 8; vv++) acc[vv] = bv;
  for (int k = 0; k < 512; k++) {
    float w = W[k * 1024 + unit];
#pragma unroll
    for (int vv = 0; vv < 8; vv++) acc[vv] += es[vv][k] * w;
  }
#pragma unroll
  for (int vv = 0; vv < 8; vv++) {
    int v = vg * 8 + vv;
    if (v < 513) P[(size_t)v * 4096 + c] = acc[vv];
  }
}

// ---------------- pack Wt[c][k] = W_{gate(c)}h[k][unit(c)] as fp16
__global__ void pack_Wt(const float* __restrict__ Wgh, const float* __restrict__ Wih,
                        const float* __restrict__ Wfh, const float* __restrict__ Woh,
                        _Float16* __restrict__ Wt) {
  const int c = blockIdx.x;
  const int gate = c & 3, unit = c >> 2;
  const float* W = gate == 0 ? Wgh : gate == 1 ? Wih : gate == 2 ? Wfh : Woh;
  for (int k = threadIdx.x; k < 1024; k += 256)
    Wt[(size_t)c * 1024 + k] = (_Float16)W[k * 1024 + unit];
}

// ---------------- persistent LSTM: 8 independent row-groups of 16 batch rows
// (R8 structure, proven). All cross-block traffic is agent-scope (LLC) — no
// placement assumptions. Changes vs R8: (1) per-block FLAG ARRAY + 32-lane
// ballot poll replaces the contended single-counter atomicAdd; (2) gate threads
// shfl-pack h and publish directly (no LDS staging barrier). 4 barriers/step.
// Protocol: [top] wave0 polls all 32 group flags >= t -> bar -> A-stage
// (sc0 sc1 direct-to-LLC loads) -> bar -> MFMA -> bar -> gates + shfl-pack
// 8B sc1 publish + x-prefetch -> bar (vmcnt drain) -> tid0 flag=t+1 (sc1).
// flag[S]=v certifies S published h_v AND finished reading h_{v-1}, so
// overwriting h_{t-1}'s buffer with h_{t+1} after the poll is race-free.
__launch_bounds__(512, 2)
__global__ void lstm_step_all(const int* __restrict__ x,
                              const float* __restrict__ P,
                              const _Float16* __restrict__ Wt,
                              _Float16* __restrict__ hbuf,
                              float* __restrict__ h32,
                              const float* __restrict__ h_init,
                              const float* __restrict__ c_init,
                              unsigned int* __restrict__ flags) {
  cg::grid_group grid = cg::this_grid();
  __shared__ _Float16 alds[16 * 1024];   // 32 KB staged A (granule-XOR swizzled)
  __shared__ float pre[16 * 132];        // 8.25 KB fp32 pre-activations
  __shared__ int xs2[2][16];
  const int tid = threadIdx.x;
  const int blk = blockIdx.x;
  const int grp = blk & 7;      // row-group
  const int sub = blk >> 3;     // 0..31 col-partition
  const int lane = tid & 63;
  const int wid = tid >> 6;
  const int l15 = lane & 15;
  const int gg = lane >> 4;
  const int kg = gg * 8;
  const int colbase = sub * 128;  // gate-col base
  const int ubase = sub * 32;     // hidden-unit base
  const int rowbase = grp * 16;   // batch-row base

  if (tid == 0)
    __hip_atomic_store(&flags[blk * FLAG_STRIDE], 0u, __ATOMIC_RELAXED,
                       __HIP_MEMORY_SCOPE_AGENT);

  // B resident in VGPRs: wave w covers cols colbase + w*16 .. +16, all K
  h8 bfr[32];
  {
    const _Float16* wp = Wt + (size_t)(colbase + wid * 16 + l15) * 1024 + kg;
#pragma unroll
    for (int s = 0; s < 32; s++) bfr[s] = *(const h8*)(wp + s * 32);
  }

  // init h0 slice (this block's 16 rows x 32 units) into buffer 0
  if (tid < 128) {
    int r16 = tid >> 3, q = tid & 7;
    union { _Float16 h[4]; ull_t u; } pk;
#pragma unroll
    for (int u = 0; u < 4; u++) pk.h[u] = (_Float16)h_init[ubase + q * 4 + u];
    *(ull_t*)&hbuf[(size_t)(rowbase + r16) * 1024 + ubase + q * 4] = pk.u;
  }
  if (tid < 16) xs2[0][tid] = x[(rowbase + tid) * 513];
  // gate-phase identity: row = tid>>5, unit = tid&31 (persistent c state)
  const int grow = tid >> 5;
  const int gu = tid & 31;
  float cst = c_init[ubase + gu];
  grid.sync();  // covers h0, flags, Wt/P reads

  for (int t = 0; t < T_STEPS; t++) {
    const _Float16* hc = hbuf + (t & 1) * (128 * 1024);
    _Float16* hn = hbuf + ((t + 1) & 1) * (128 * 1024);

    // exact-P gather issued early; latency hides under poll window
    const float* prow = P + (size_t)xs2[t & 1][grow] * 4096 + colbase + gu * 4;
    f4 pv = *(const f4*)prow;

    // ---- poll: wave0's lanes 0..31 watch the group's 32 per-block flags (LLC)
    if (tid < 64) {
      const unsigned* fp = &flags[(grp + 8 * (lane & 31)) * FLAG_STRIDE];
      const unsigned tgt = (unsigned)t;
      for (;;) {
        unsigned f = tgt;
        if (lane < 32) {
          asm volatile("global_load_dword %0, %1, off sc0 sc1\n\ts_waitcnt vmcnt(0)"
                       : "=v"(f) : "v"(fp) : "memory");
        }
        if (__ballot(f >= tgt) == ~0ull) break;
        __builtin_amdgcn_s_sleep(1);
      }
    }
    __syncthreads();

    // ---- A-stage: 16 rows x 2KB via direct-to-LLC loads (bypass stale L1/L2).
    // 128 consecutive threads read one row's contiguous 2KB -> fully coalesced.
    {
      i32x4 av[4];
#pragma unroll
      for (int r = 0; r < 4; r++) {
        int idx = r * 512 + tid;
        int ar = idx >> 7, g = idx & 127;
        const _Float16* p = &hc[(size_t)(rowbase + ar) * 1024 + g * 8];
        asm volatile("global_load_dwordx4 %0, %1, off sc0 sc1"
                     : "=v"(av[r]) : "v"(p) : "memory");
      }
      asm volatile("s_waitcnt vmcnt(0)" ::: "memory");
      __builtin_amdgcn_sched_barrier(0);
#pragma unroll
      for (int r = 0; r < 4; r++) {
        int idx = r * 512 + tid;
        int ar = idx >> 7, g = idx & 127;
        *(i32x4*)&alds[ar * 1024 + ((g ^ (ar & 7)) * 8)] = av[r];
      }
    }
    __syncthreads();

    // ---- MFMA: 16 rows x 16 cols x K=1024, B from regs, 4 acc chains
    f4 ac0 = {0.f, 0.f, 0.f, 0.f}, ac1 = ac0, ac2 = ac0, ac3 = ac0;
#pragma unroll
    for (int s = 0; s < 32; s++) {
      int g = s * 4 + gg;
      h8 a = *(const h8*)&alds[l15 * 1024 + ((g ^ (l15 & 7)) * 8)];
      if ((s & 3) == 0) ac0 = __builtin_amdgcn_mfma_f32_16x16x32_f16(a, bfr[s], ac0, 0, 0, 0);
      else if ((s & 3) == 1) ac1 = __builtin_amdgcn_mfma_f32_16x16x32_f16(a, bfr[s], ac1, 0, 0, 0);
      else if ((s & 3) == 2) ac2 = __builtin_amdgcn_mfma_f32_16x16x32_f16(a, bfr[s], ac2, 0, 0, 0);
      else ac3 = __builtin_amdgcn_mfma_f32_16x16x32_f16(a, bfr[s], ac3, 0, 0, 0);
    }
    f4 acc = (ac0 + ac1) + (ac2 + ac3);
#pragma unroll
    for (int i = 0; i < 4; i++)
      pre[(gg * 4 + i) * 132 + wid * 16 + l15] = acc[i];
    __syncthreads();

    // ---- gates: all 512 threads (16 rows x 32 units); shfl-pack h and
    // publish 8B per 4-lane leader directly (no LDS staging barrier)
    {
      f4 q = *(const f4*)&pre[grow * 132 + gu * 4];
      q += pv;
      float g_ = tanh_fast(q[0]);
      float i_ = sigm(q[1]);
      float f_ = sigm(q[2]);
      float o_ = sigm(q[3]);
      cst = g_ * i_ + cst * f_;
      float hv = tanh_fast(cst) * o_;
      if (t == T_STEPS - 1) {
        h32[(size_t)(rowbase + grow) * 1024 + ubase + gu] = hv;
      } else {
        union { _Float16 hh; unsigned short us; } cv;
        cv.hh = (_Float16)hv;
        unsigned v0 = cv.us;
        unsigned v1 = (unsigned)__shfl_down((int)v0, 1);
        unsigned lo = (v0 & 0xffffu) | (v1 << 16);
        unsigned lo2 = (unsigned)__shfl_down((int)lo, 2);
        if ((gu & 3) == 0) {
          ull_t pv8 = (ull_t)lo | ((ull_t)lo2 << 32);
          __hip_atomic_store((ull_t*)&hn[(size_t)(rowbase + grow) * 1024 + ubase + gu],
                             pv8, __ATOMIC_RELAXED, __HIP_MEMORY_SCOPE_AGENT);
        }
      }
    }
    if (t == T_STEPS - 1) break;
    if (tid < 16) xs2[(t + 1) & 1][tid] = x[(rowbase + tid) * 513 + (t + 1)];
    __syncthreads();  // vmcnt drain: publish stores ack'd at LLC before flag

    // ---- publish flag: any observer of flag >= t+1 sees h_{t+1} at LLC
    if (tid == 0)
      __hip_atomic_store(&flags[blk * FLAG_STRIDE], (unsigned)(t + 1),
                         __ATOMIC_RELAXED, __HIP_MEMORY_SCOPE_AGENT);
  }
}

// ---------------- final projection p = h_T @ W_ph + b_p (fp32)
__global__ void proj(const float* __restrict__ h32, const float* __restrict__ Wph,
                     const float* __restrict__ bp, float* __restrict__ logits) {
  const int b = blockIdx.x >> 1;
  const int cc = (blockIdx.x & 1) * 256 + threadIdx.x;
  const float* hrow = h32 + b * 1024;
  float acc = bp[cc];
#pragma unroll 4
  for (int k = 0; k < 1024; k++) acc += hrow[k] * Wph[k * 512 + cc];
  logits[b * 512 + cc] = acc;
}

// ---------------- row-wise log_softmax
__global__ void lsm(const float* __restrict__ logits, float* __restrict__ out) {
  const int b = blockIdx.x;
  const int tid = threadIdx.x;
  __shared__ float sm[4];
  __shared__ float se[4];
  float v0 = logits[b * 512 + tid];
  float v1 = logits[b * 512 + 256 + tid];
  float m = fmaxf(v0, v1);
  for (int o = 1; o < 64; o <<= 1) m = fmaxf(m, __shfl_xor(m, o, 64));
  if ((tid & 63) == 0) sm[tid >> 6] = m;
  __syncthreads();
  m = fmaxf(fmaxf(sm[0], sm[1]), fmaxf(sm[2], sm[3]));
  float e = expf(v0 - m) + expf(v1 - m);
  for (int o = 1; o < 64; o <<= 1) e += __shfl_xor(e, o, 64);
  if ((tid & 63) == 0) se[tid >> 6] = e;
  __syncthreads();
  float ls = logf(se[0] + se[1] + se[2] + se[3]) + m;
  out[b * 512 + tid] = v0 - ls;
  out[b * 512 + 256 + tid] = v1 - ls;
}

extern "C" void kernel_launch(void* const* d_in, const int* in_sizes, int n_in,
                              void* d_out, int out_size, void* d_ws, size_t ws_size,
                              hipStream_t stream) {
  const int* x = (const int*)d_in[0];
  const float* emb = (const float*)d_in[1];
  const float* Wgx = (const float*)d_in[2];
  const float* Wgh = (const float*)d_in[3];
  const float* bg = (const float*)d_in[4];
  const float* Wix = (const float*)d_in[5];
  const float* Wih = (const float*)d_in[6];
  const float* bi = (const float*)d_in[7];
  const float* Wfx = (const float*)d_in[8];
  const float* Wfh = (const float*)d_in[9];
  const float* bf = (const float*)d_in[10];
  const float* Wox = (const float*)d_in[11];
  const float* Woh = (const float*)d_in[12];
  const float* bo = (const float*)d_in[13];
  const float* Wph = (const float*)d_in[14];
  const float* bp = (const float*)d_in[15];
  const float* h_init = (const float*)d_in[16];
  const float* c_init = (const float*)d_in[17];

  char* ws = (char*)d_ws;
  float* P = (float*)ws;                                   // 520*4096*4   = 8,519,680
  unsigned int* flags = (unsigned int*)(ws + (size_t)513 * 4096 * 4);  // 16 KB (P pad)
  _Float16* Wt = (_Float16*)(ws + 8519680);                // 4096*1024*2  = 8,388,608
  _Float16* hbuf = (_Float16*)(ws + 8519680 + 8388608);    // 2*128*1024*2 = 524,288
  float* h32 = (float*)(ws + 8519680 + 8388608 + 524288);  // 128*1024*4   = 524,288
  float* logits = (float*)(ws + 8519680 + 8388608 + 524288 + 524288);  // 128*512*4

  pack_P<<<dim3(65, 16), 256, 0, stream>>>(emb, Wgx, Wix, Wfx, Wox, bg, bi, bf, bo, P);
  pack_Wt<<<4096, 256, 0, stream>>>(Wgh, Wih, Wfh, Woh, Wt);

  void* args[] = {(void*)&x, (void*)&P, (void*)&Wt, (void*)&hbuf,
                  (void*)&h32, (void*)&h_init, (void*)&c_init, (void*)&flags};
  hipLaunchCooperativeKernel((void*)lstm_step_all, dim3(NBLK), dim3(512), args, 0, stream);

  proj<<<256, 256, 0, stream>>>(h32, Wph, bp, logits);
  lsm<<<128, 256, 0, stream>>>(logits, (float*)d_out);
}